// Round 8
// baseline (4150.674 us; speedup 1.0000x reference)
//
#include <hip/hip_runtime.h>

typedef __bf16 bf16x8 __attribute__((ext_vector_type(8)));
typedef float  f32x4  __attribute__((ext_vector_type(4)));

#define Z0S 520   // z0 row (elems): [h_row 0:256 | h_col 256:512 | x 512:520]
#define Z1S 1032  // z1 row: [h_row | h_col | x_row 512:768 | x_col 768:1024] + 8 pad
#define W0P_ELEMS (2 * 8 * 17 * 6 * 512)   // packed W0: [gcg 0..15][ks0..16][G][lane][8]
#define W1P_ELEMS (2 * 8 * 32 * 6 * 512)   // packed W1: [gcg 0..15][ks0..31][G][lane][8]
#define XB_ELEMS (2 * 64 * 32 * 512)       // [slot][b][m][c] bf16, c = region*256+col

__device__ __forceinline__ unsigned short f2bf(float f) {
    unsigned int u = __builtin_bit_cast(unsigned int, f);
    u += 0x7fffu + ((u >> 16) & 1u);   // RNE
    return (unsigned short)(u >> 16);
}
__device__ __forceinline__ float sigm(float x) {
    x = fminf(30.f, fmaxf(-30.f, x));
    return __fdividef(1.0f, 1.0f + __expf(-x));
}
__device__ __forceinline__ float ftanh(float x) {
    x = fminf(15.f, fmaxf(-15.f, x));
    float e = __expf(2.0f * x);
    return 1.0f - __fdividef(2.0f, e + 1.0f);
}
__device__ __forceinline__ bf16x8 zero8() {
    bf16x8 v;
#pragma unroll
    for (int i = 0; i < 8; ++i) v[i] = (__bf16)0.0f;
    return v;
}
// L2-bypassing stores (write-through): output/exchange streams must NOT
// allocate in L2 (round-3/4: write streams were evicting the weight slice).
__device__ __forceinline__ void st_f32_wt(float* p, float v) {
    __hip_atomic_store(p, v, __ATOMIC_RELAXED, __HIP_MEMORY_SCOPE_AGENT);
}
__device__ __forceinline__ void st_u16_wt(unsigned short* p, unsigned short v) {
    __hip_atomic_store(p, v, __ATOMIC_RELAXED, __HIP_MEMORY_SCOPE_AGENT);
}

// fp32 -> bf16 weight conversion + MFMA-fragment packing + flag zeroing.
__global__ void convert_w(const float* __restrict__ W0f, const float* __restrict__ W1f,
                          unsigned short* __restrict__ W0p, unsigned short* __restrict__ W1p,
                          int* __restrict__ flags) {
    const int gid = blockIdx.x * blockDim.x + threadIdx.x;
    const int stride = gridDim.x * blockDim.x;
    if (gid < 512) flags[gid] = 0;
    for (int i = gid; i < W0P_ELEMS; i += stride) {
        const int e = i & 7, lane = (i >> 3) & 63;
        const int r = i >> 9;
        const int G = r % 6;  const int r2 = r / 6;
        const int ks = r2 % 17; const int gcg = r2 / 17;    // 0..15
        const int jj = gcg * 16 + (lane & 15);
        const int k = ks * 32 + (lane >> 4) * 8 + e;
        float v = 0.f;
        if (k < 520) v = W0f[(size_t)(G * 256 + jj) * 520 + k];
        W0p[i] = f2bf(v);
    }
    for (int i = gid; i < W1P_ELEMS; i += stride) {
        const int e = i & 7, lane = (i >> 3) & 63;
        const int r = i >> 9;
        const int G = r % 6;  const int r2 = r / 6;
        const int ks = r2 & 31; const int gcg = r2 >> 5;    // 0..15
        const int jj = gcg * 16 + (lane & 15);
        const int k = ks * 32 + (lane >> 4) * 8 + e;
        W1p[i] = f2bf(W1f[(size_t)(G * 256 + jj) * 1024 + k]);
    }
}

// 256 blocks = 64 batches x 4 column-slices; 1024 threads = 16 waves =
// 4 col-groups x 2 gate-halves x 2 K-HALVES (round 8 change). Round-7 PMC:
// no longer delivery-bound (1.18 MB/step/CU ~ 8.7 us at L2 share vs 29 us
// measured) but LATENCY-bound at 2 waves/SIMD (Occ 24%, busy ~40%). K-split
// doubles waves/SIMD to 4 with ZERO extra weight traffic: wave (cg,gh,kh)
// computes K-half kh of both m-tiles, then the kh-pair reduces partials via
// LDS (red buffer) and each wave owns m-tile mh=kh for gating/epilogue.
// Old B1 barrier subsumed by the reduction barrier. Exchange protocol
// (write-through publish, relaxed agent-scope loads, capped spins) unchanged.
__global__ __launch_bounds__(1024, 4) void witran_coop(
    const float* __restrict__ inp,             // (64,32,32,8) fp32
    const unsigned short* __restrict__ W0p,    // packed bf16
    const unsigned short* __restrict__ W1p,    // packed bf16
    const float* __restrict__ Bias,            // (2,1536)    fp32
    float* __restrict__ out,                   // fp32 outputs
    unsigned short* __restrict__ xb0,          // exchange: layer-0 images
    unsigned short* __restrict__ xb1,          // exchange: layer-1 state
    int* __restrict__ flags)                   // [256] f0 | [256] f1
{
    const int bid  = blockIdx.x;
    const int r8   = bid & 7;
    const int s    = r8 >> 1;                        // slice 0..3 (XCD pair)
    const int b    = (bid >> 3) * 2 + (r8 & 1);      // batch 0..63
    const int tid  = threadIdx.x;
    const int wave = tid >> 6;                       // 0..15
    const int cg   = wave >> 2;                      // col-group 0..3
    const int gh   = (wave >> 1) & 1;                // 0 = row-wave, 1 = col-wave
    const int kh   = wave & 1;                       // K-half / owned m-tile
    const int lane = tid & 63;
    const int quad = lane >> 4;
    const int l16  = lane & 15;
    const int jl   = cg * 16 + l16;                  // local col 0..63
    const int jj   = s * 64 + jl;                    // absolute col 0..255
    const int gcg  = jj >> 4;                        // global col-group 0..15
    // gate set: row {0,1,4} = {u_r,o_r,i_r}; col {2,3,5} = {u_c,o_c,i_c}
    const int Gs0 = 2 * gh, Gs1 = 2 * gh + 1, Gs2 = 4 + gh;

    int* f0 = flags;
    int* f1 = flags + 256;
    const int fown = b * 4 + s;

    __shared__ __align__(16) unsigned short z0[32 * Z0S];    // 33280 B
    __shared__ __align__(16) unsigned short z1[32 * Z1S];    // 66048 B
    __shared__ float rollbuf[32 * 64];                       //  8192 B
    __shared__ __align__(16) float red[16 * 3 * 64 * 4];     // 49152 B [wave][i][lane][4]

    for (int idx = tid; idx < 32 * Z0S; idx += 1024) z0[idx] = 0;
    for (int idx = tid; idx < 32 * Z1S; idx += 1024) z1[idx] = 0;
    __syncthreads();
    if (tid < 256) {                           // stage x for t=0
        const int m = tid >> 3, i = tid & 7;
        const int c = 0 - m;
        float v = 0.f;
        if (c >= 0 && c < 32) v = inp[((b * 32 + m) * 32 + c) * 8 + i];
        z0[m * Z0S + 512 + i] = f2bf(v);
    }

    float biasr[2][3];
#pragma unroll
    for (int L = 0; L < 2; ++L) {
        biasr[L][0] = Bias[L * 1536 + Gs0 * 256 + jj];
        biasr[L][1] = Bias[L * 1536 + Gs1 * 256 + jj];
        biasr[L][2] = Bias[L * 1536 + Gs2 * 256 + jj];
    }

    // own-state regs for the owned m-tile (mh = kh) only:
    // streg[L][p] <-> row m = kh*16+quad*4+p, col jj (h_row if gh=0, h_col if gh=1)
    float streg[2][4];
#pragma unroll
    for (int L = 0; L < 2; ++L)
#pragma unroll
        for (int p = 0; p < 4; ++p) streg[L][p] = 0.f;

    // wave-level packed weight bases (3 gate groups); frag = contiguous 1 KB
    const unsigned short* w0g[3];
    const unsigned short* w1g[3];
    w0g[0] = W0p + (size_t)gcg * (17 * 6 * 512) + Gs0 * 512 + lane * 8;
    w0g[1] = W0p + (size_t)gcg * (17 * 6 * 512) + Gs1 * 512 + lane * 8;
    w0g[2] = W0p + (size_t)gcg * (17 * 6 * 512) + Gs2 * 512 + lane * 8;
    w1g[0] = W1p + (size_t)gcg * (32 * 6 * 512) + Gs0 * 512 + lane * 8;
    w1g[1] = W1p + (size_t)gcg * (32 * 6 * 512) + Gs1 * 512 + lane * 8;
    w1g[2] = W1p + (size_t)gcg * (32 * 6 * 512) + Gs2 * 512 + lane * 8;
    const unsigned short* aB0m[2] = { &z0[l16 * Z0S], &z0[(16 + l16) * Z0S] };
    const unsigned short* aB1m[2] = { &z1[l16 * Z1S], &z1[(16 + l16) * Z1S] };

    // reduction slots: my write slot = wave; my read slot = wave^1 (kh partner)
    float* redw = &red[(wave * 3) * 256 + lane * 4];
    const float* redr = &red[((wave ^ 1) * 3) * 256 + lane * 4];

    __syncthreads();

    const size_t OUT1 = 66060288u;           // hidden_row_all (64,2,32,256)
    const size_t OUT2 = OUT1 + 1048576u;     // hidden_col_all (64,2,32,256)

    // partner-staging decomposition: 1024 threads = 2 buffer-paths x 512
    // (512 = 32 rows x 2 regions x 8 chunks)
    const int bsel = tid >> 9;               // 0: xb0 path, 1: xb1 path
    const int t9   = tid & 511;
    const int sr   = t9 >> 4;                // row 0..31
    const int srem = t9 & 15;
    const int sreg = srem >> 3;              // 0 = h_row, 1 = h_col
    const int sc8  = (srem & 7) * 8;         // chunk offset within 64-col slice
    const int sr1  = (sr + 1) & 31;

    for (int t = 0; t < 63; ++t) {
        float snew[4];
        f32x4 acc[3][2];
        bf16x8 bA[3], bB[3];

        // ============ phase A: GEMM0 (reads z0), K-half kh ============
#pragma unroll
        for (int i = 0; i < 3; ++i)
#pragma unroll
            for (int mh = 0; mh < 2; ++mh) acc[i][mh] = (f32x4){0.f, 0.f, 0.f, 0.f};
        {
            const int ka = kh ? 9 : 0;
            const int kb = kh ? 16 : 9;      // full ks in [ka,kb); kh=1 adds partial ks16
#pragma unroll
            for (int i = 0; i < 3; ++i) bA[i] = *(const bf16x8*)&w0g[i][ka * 3072];
#pragma unroll 2
            for (int ks = ka; ks < kb; ++ks) {
                bf16x8 a0 = *(const bf16x8*)&aB0m[0][ks * 32 + quad * 8];
                bf16x8 a1 = *(const bf16x8*)&aB0m[1][ks * 32 + quad * 8];
                const int kn = (ks + 1 < kb) ? ks + 1 : ks;
#pragma unroll
                for (int i = 0; i < 3; ++i) bB[i] = *(const bf16x8*)&w0g[i][kn * 3072];
#pragma unroll
                for (int i = 0; i < 3; ++i) {
                    acc[i][0] = __builtin_amdgcn_mfma_f32_16x16x32_bf16(a0, bA[i], acc[i][0], 0, 0, 0);
                    acc[i][1] = __builtin_amdgcn_mfma_f32_16x16x32_bf16(a1, bA[i], acc[i][1], 0, 0, 0);
                }
#pragma unroll
                for (int i = 0; i < 3; ++i) bA[i] = bB[i];
            }
            if (kh) {   // partial ks16: x cols 512..519 on quad 0; B zero-padded
                bf16x8 a0 = zero8(), a1 = zero8();
                if (quad == 0) {
                    a0 = *(const bf16x8*)&aB0m[0][512];
                    a1 = *(const bf16x8*)&aB0m[1][512];
                }
#pragma unroll
                for (int i = 0; i < 3; ++i) bB[i] = *(const bf16x8*)&w0g[i][16 * 3072];
#pragma unroll
                for (int i = 0; i < 3; ++i) {
                    acc[i][0] = __builtin_amdgcn_mfma_f32_16x16x32_bf16(a0, bB[i], acc[i][0], 0, 0, 0);
                    acc[i][1] = __builtin_amdgcn_mfma_f32_16x16x32_bf16(a1, bB[i], acc[i][1], 0, 0, 0);
                }
            }
        }
        // cross-wave K-reduction: give away the non-owned m-tile partial
#pragma unroll
        for (int i = 0; i < 3; ++i) *(f32x4*)&redw[i * 256] = acc[i][1 - kh];
        __syncthreads();   // R1(L0): also orders all z0 reads before phase-B writes
#pragma unroll
        for (int i = 0; i < 3; ++i) {
            const f32x4 v = *(const f32x4*)&redr[i * 256];
            acc[i][kh][0] += v[0]; acc[i][kh][1] += v[1];
            acc[i][kh][2] += v[2]; acc[i][kh][3] += v[3];
        }
#pragma unroll
        for (int p = 0; p < 4; ++p) {
            const int m = kh * 16 + quad * 4 + p;
            float gu = acc[0][kh][p], go = acc[1][kh][p], gi = acc[2][kh][p];
            if ((t < 32) && (m <= t)) {
                gu += biasr[0][0]; go += biasr[0][1]; gi += biasr[0][2];
            }
            const float u = sigm(gu), o = sigm(go), ii = ftanh(gi);
            snew[p] = ftanh((1.f - u) * streg[0][p] + u * ii) * o;
        }
        if (gh == 0) {   // row state updates immediately; col state via rollbuf roll
#pragma unroll
            for (int p = 0; p < 4; ++p) streg[0][p] = snew[p];
        }

        // ============ phase B: layer-0 epilogue + publish (own m-tile) ============
#pragma unroll
        for (int p = 0; p < 4; ++p) {
            const int m  = kh * 16 + quad * 4 + p;
            const float f = snew[p];
            const unsigned short hb = f2bf(f);
            const size_t xi = ((size_t)((t & 1) * 64 + b) * 32 + m) * 512;
            if (gh == 0) {   // h_row side
                z0[m * Z0S + jj] = hb;
                z1[m * Z1S + 512 + jj] = hb;             // layer-1 x_row
                st_u16_wt(&xb0[xi + jj], hb);
                if (t >= 31 && m == t - 31)
                    st_f32_wt(&out[OUT1 + ((size_t)(b * 2 + 0) * 32 + (t - 31)) * 256 + jj], f);
            } else {         // h_col side
                z0[((m + 1) & 31) * Z0S + 256 + jj] = hb; // rolled h_col
                z1[m * Z1S + 768 + jj] = hb;              // layer-1 x_col (unrolled)
                rollbuf[m * 64 + jl] = f;
                st_u16_wt(&xb0[xi + 256 + jj], hb);
                if (t >= 31 && m == 31)
                    st_f32_wt(&out[OUT2 + ((size_t)(b * 2 + 0) * 32 + (t - 31)) * 256 + jj], f);
            }
        }
        if (tid < 256 && t + 1 < 63) {     // stage x for t+1
            const int m = tid >> 3, i = tid & 7;
            const int c = t + 1 - m;
            float v = 0.f;
            if (c >= 0 && c < 32) v = inp[((b * 32 + m) * 32 + c) * 8 + i];
            z0[m * Z0S + 512 + i] = f2bf(v);
        }
        __syncthreads();   // B2a: own writes done (s_barrier drains vmcnt)

        if (tid == 0)
            __hip_atomic_store(&f0[fown], t + 1, __ATOMIC_RELEASE, __HIP_MEMORY_SCOPE_AGENT);

        // roll readback, layer 0 (col-waves): new h_col[m] = computed[(m-1) mod 32]
        if (gh == 1) {
#pragma unroll
            for (int p = 0; p < 4; ++p) {
                const int m = kh * 16 + quad * 4 + p;
                streg[0][p] = rollbuf[((m + 31) & 31) * 64 + jl];
            }
        }

        // wait for 3 partner slices: layer-0 step t, layer-1 step t-1.
        if (tid == 0) {
#pragma unroll
            for (int j = 1; j < 4; ++j) {
                const int fp = b * 4 + ((s + j) & 3);
                int it = 0;
                while (__hip_atomic_load(&f0[fp], __ATOMIC_RELAXED, __HIP_MEMORY_SCOPE_AGENT) < t + 1) {
                    __builtin_amdgcn_s_sleep(4);
                    if (++it > 4000000) break;
                }
                it = 0;
                while (__hip_atomic_load(&f1[fp], __ATOMIC_RELAXED, __HIP_MEMORY_SCOPE_AGENT) < t) {
                    __builtin_amdgcn_s_sleep(4);
                    if (++it > 4000000) break;
                }
            }
        }
        __syncthreads();   // Bp: partner-ready fact visible to all waves

        // partner staging: path 0 = xb0 -> z1-x + z0-state; path 1 = xb1 -> z1-state
        {
            const unsigned int* x0u = (const unsigned int*)xb0;
            const unsigned int* x1u = (const unsigned int*)xb1;
#pragma unroll
            for (int j = 1; j < 4; ++j) {
                const int q   = (s + j) & 3;
                const int col = q * 64 + sc8;
                union { unsigned int u4[4]; bf16x8 v; } qv;
                if (bsel == 0) {
                    const size_t e0 = (((size_t)((t & 1) * 64 + b) * 32 + sr) * 512 + sreg * 256 + col) >> 1;
#pragma unroll
                    for (int w = 0; w < 4; ++w)
                        qv.u4[w] = __hip_atomic_load(&x0u[e0 + w], __ATOMIC_RELAXED, __HIP_MEMORY_SCOPE_AGENT);
                    // layer-0 image (step t): z1 x-region (no roll) + z0 state (hcol rolled)
                    *(bf16x8*)&z1[sr * Z1S + 512 + sreg * 256 + col] = qv.v;
                    *(bf16x8*)&z0[(sreg ? sr1 : sr) * Z0S + sreg * 256 + col] = qv.v;
                } else if (t > 0) {   // layer-1 state (step t-1): hcol rolled
                    const size_t e1 = (((size_t)(((t + 1) & 1) * 64 + b) * 32 + sr) * 512 + sreg * 256 + col) >> 1;
#pragma unroll
                    for (int w = 0; w < 4; ++w)
                        qv.u4[w] = __hip_atomic_load(&x1u[e1 + w], __ATOMIC_RELAXED, __HIP_MEMORY_SCOPE_AGENT);
                    *(bf16x8*)&z1[(sreg ? sr1 : sr) * Z1S + sreg * 256 + col] = qv.v;
                }
            }
        }
        __syncthreads();   // B2b: z1 fully staged

        // ============ phase C: GEMM1 (reads z1), K-half kh ============
#pragma unroll
        for (int i = 0; i < 3; ++i)
#pragma unroll
            for (int mh = 0; mh < 2; ++mh) acc[i][mh] = (f32x4){0.f, 0.f, 0.f, 0.f};
        {
            const int ka = kh ? 16 : 0;
            const int kb = kh ? 32 : 16;
#pragma unroll
            for (int i = 0; i < 3; ++i) bA[i] = *(const bf16x8*)&w1g[i][ka * 3072];
#pragma unroll 2
            for (int ks = ka; ks < kb; ++ks) {
                bf16x8 a0 = *(const bf16x8*)&aB1m[0][ks * 32 + quad * 8];
                bf16x8 a1 = *(const bf16x8*)&aB1m[1][ks * 32 + quad * 8];
                const int kn = (ks + 1 < kb) ? ks + 1 : ks;
#pragma unroll
                for (int i = 0; i < 3; ++i) bB[i] = *(const bf16x8*)&w1g[i][kn * 3072];
#pragma unroll
                for (int i = 0; i < 3; ++i) {
                    acc[i][0] = __builtin_amdgcn_mfma_f32_16x16x32_bf16(a0, bA[i], acc[i][0], 0, 0, 0);
                    acc[i][1] = __builtin_amdgcn_mfma_f32_16x16x32_bf16(a1, bA[i], acc[i][1], 0, 0, 0);
                }
#pragma unroll
                for (int i = 0; i < 3; ++i) bA[i] = bB[i];
            }
        }
        // cross-wave K-reduction
#pragma unroll
        for (int i = 0; i < 3; ++i) *(f32x4*)&redw[i * 256] = acc[i][1 - kh];
        __syncthreads();   // R1(L1): also orders all z1 reads before phase-D writes
#pragma unroll
        for (int i = 0; i < 3; ++i) {
            const f32x4 v = *(const f32x4*)&redr[i * 256];
            acc[i][kh][0] += v[0]; acc[i][kh][1] += v[1];
            acc[i][kh][2] += v[2]; acc[i][kh][3] += v[3];
        }
#pragma unroll
        for (int p = 0; p < 4; ++p) {
            const int m = kh * 16 + quad * 4 + p;
            float gu = acc[0][kh][p], go = acc[1][kh][p], gi = acc[2][kh][p];
            if ((t < 32) && (m <= t)) {
                gu += biasr[1][0]; go += biasr[1][1]; gi += biasr[1][2];
            }
            const float u = sigm(gu), o = sigm(go), ii = ftanh(gi);
            snew[p] = ftanh((1.f - u) * streg[1][p] + u * ii) * o;
        }
        if (gh == 0) {
#pragma unroll
            for (int p = 0; p < 4; ++p) streg[1][p] = snew[p];
        }

        // ============ phase D: layer-1 epilogue + publish (own m-tile) ============
#pragma unroll
        for (int p = 0; p < 4; ++p) {
            const int m  = kh * 16 + quad * 4 + p;
            const float f = snew[p];
            const unsigned short hb = f2bf(f);
            const size_t xi = ((size_t)((t & 1) * 64 + b) * 32 + m) * 512;
            const size_t row = (size_t)(m * 64 + b);
            if (gh == 0) {   // h_row side
                z1[m * Z1S + jj] = hb;
                st_u16_wt(&xb1[xi + jj], hb);
                st_f32_wt(&out[(row * 63 + t) * 512 + jj], f);          // output_all row half
                if (t >= 31 && m == t - 31)
                    st_f32_wt(&out[OUT1 + ((size_t)(b * 2 + 1) * 32 + (t - 31)) * 256 + jj], f);
            } else {         // h_col side
                z1[((m + 1) & 31) * Z1S + 256 + jj] = hb;
                rollbuf[m * 64 + jl] = f;
                st_u16_wt(&xb1[xi + 256 + jj], hb);
                st_f32_wt(&out[(row * 63 + t) * 512 + 256 + jj], f);    // output_all col half
                if (t >= 31 && m == 31)
                    st_f32_wt(&out[OUT2 + ((size_t)(b * 2 + 1) * 32 + (t - 31)) * 256 + jj], f);
            }
        }
        __syncthreads();   // B4: z1 state + rollbuf published (vmcnt drained)

        if (tid == 0)
            __hip_atomic_store(&f1[fown], t + 1, __ATOMIC_RELEASE, __HIP_MEMORY_SCOPE_AGENT);

        if (gh == 1) {   // roll readback, layer 1
#pragma unroll
            for (int p = 0; p < 4; ++p) {
                const int m = kh * 16 + quad * 4 + p;
                streg[1][p] = rollbuf[((m + 31) & 31) * 64 + jl];
            }
        }
    }
}

extern "C" void kernel_launch(void* const* d_in, const int* in_sizes, int n_in,
                              void* d_out, int out_size, void* d_ws, size_t ws_size,
                              hipStream_t stream) {
    (void)in_sizes; (void)n_in; (void)out_size; (void)ws_size;
    const float* inp   = (const float*)d_in[0];   // (64,32,32,8) fp32
    const float* W0f   = (const float*)d_in[1];   // (1536,520)  fp32
    const float* W1f   = (const float*)d_in[2];   // (1,1536,1024) fp32
    const float* Biasf = (const float*)d_in[3];   // (2,1536) fp32
    float* out = (float*)d_out;

    // ws layout (~13.2 MB): [W0p bf16 | W1p bf16 | flags 512 int | xb0 | xb1]
    unsigned short* W0p = (unsigned short*)d_ws;
    unsigned short* W1p = W0p + W0P_ELEMS;
    int* flags = (int*)(W1p + W1P_ELEMS);
    unsigned short* xb0 = (unsigned short*)(flags + 512);
    unsigned short* xb1 = xb0 + XB_ELEMS;

    convert_w<<<dim3(512), dim3(256), 0, stream>>>(W0f, W1f, W0p, W1p, flags);
    witran_coop<<<dim3(256), dim3(1024), 0, stream>>>(inp, W0p, W1p, Biasf, out,
                                                      xb0, xb1, flags);
}